// Round 9
// baseline (175.098 us; speedup 1.0000x reference)
//
#include <hip/hip_runtime.h>

#define NS 5      // symbols
#define NW 33     // subcarriers
#define NA 16     // antennas
#define SW 165    // NS*NW
#define BUFS 99   // per-matrix LDS buffer (f2): x rows chunk (<=99), then T2 (99)
#define NFR 17    // Fsub rows stored (0..16; F symmetric + conj-mirror covers rest)
#define SFS (NFR*NW)   // 561
#define MPW 5     // matrices per wave
#define GM 20     // matrices per block
#define TPM 11    // threads per matrix
#define CPT 3     // columns per thread
#define THREADS 256

// t-row chunks: chunk0 = t{0,1,2} full rows, chunk1 = t{3,4} full rows.
#define C0T 3
#define C0E (C0T*NW*MPW)   // 495
#define IT0 8
#define C1T 2
#define C1E (C1T*NW*MPW)   // 330
#define IT1 6

// R18: exploit Fsub symmetry (F = F^T, DFT matrix). Stage A reads rows 0..16;
// stage E's F[q][v] = F[v][q] -> the SAME 561 elements. sFsub shrinks 1089->561
// f2: F-staging loads halve, LDS 25.1->20.6 KB -> 7 blocks/CU (28 waves, was
// 20) under launch_bounds(256,7) (cap ~73 VGPR; we measure 48 -> no spill
// expected; WRITE_SIZE is the tripwire). Kept: conj-pair math + (un)spill
// discipline (R16/R17), chunk1 reg-prefetch (R17), 99-f2 LDS layout (R13),
// pk_fma (R11), wave-autonomy (R10), LDS-coalesced staging (R12 lesson).
typedef float f2 __attribute__((ext_vector_type(2)));

// z += u * Re(f):  (z.x += u.x*f.lo, z.y += u.y*f.lo)
__device__ __forceinline__ void cmac_re(f2& z, f2 u, f2 f) {
    asm("v_pk_fma_f32 %0, %1, %2, %0 op_sel:[0,0,0] op_sel_hi:[1,0,1]"
        : "+v"(z) : "v"(u), "v"(f));
}
// z += i * d * Im(f):  (z.x += -d.y*f.hi, z.y += d.x*f.hi)
__device__ __forceinline__ void cmac_im(f2& z, f2 d, f2 f) {
    asm("v_pk_fma_f32 %0, %1, %2, %0 op_sel:[1,1,0] op_sel_hi:[0,1,1] neg_lo:[1,0,0]"
        : "+v"(z) : "v"(d), "v"(f));
}
// z += conj(f) * P, P real pair Pp=(P,P): lo zr+=f.x*P, hi zi+=-f.y*P
__device__ __forceinline__ void cmacr(f2& z, f2 f, f2 Pp) {
    asm("v_pk_fma_f32 %0, %1, %2, %0 op_sel:[0,0,0] op_sel_hi:[1,1,1] neg_hi:[1,0,0]"
        : "+v"(z) : "v"(f), "v"(Pp));
}
// plain packed: z += a*b elementwise
__device__ __forceinline__ void pkfma(f2& z, f2 a, f2 b) {
    asm("v_pk_fma_f32 %0, %1, %2, %0 op_sel:[0,0,0] op_sel_hi:[1,1,1]"
        : "+v"(z) : "v"(a), "v"(b));
}
// r = a + b (packed)
__device__ __forceinline__ f2 pkadd(f2 a, f2 b) {
    f2 r; asm("v_pk_add_f32 %0, %1, %2" : "=v"(r) : "v"(a), "v"(b)); return r;
}
// r = a - b (packed)
__device__ __forceinline__ f2 pksub(f2 a, f2 b) {
    f2 r; asm("v_pk_add_f32 %0, %1, %2 neg_lo:[0,1] neg_hi:[0,1]"
              : "=v"(r) : "v"(a), "v"(b)); return r;
}
// r = (a.x + b.x, a.y - b.y)
__device__ __forceinline__ f2 pkaddsub(f2 a, f2 b) {
    f2 r; asm("v_pk_add_f32 %0, %1, %2 neg_hi:[0,1]"
              : "=v"(r) : "v"(a), "v"(b)); return r;
}
// r = u * Re(f) broadcast: (u.x*f.lo, u.y*f.lo)  -- accumulator init
__device__ __forceinline__ f2 pkmul_re(f2 u, f2 f) {
    f2 r; asm("v_pk_mul_f32 %0, %1, %2 op_sel:[0,0] op_sel_hi:[1,0]"
              : "=v"(r) : "v"(u), "v"(f)); return r;
}
// r = a * b elementwise -- accumulator init
__device__ __forceinline__ f2 pkmul(f2 a, f2 b) {
    f2 r; asm("v_pk_mul_f32 %0, %1, %2" : "=v"(r) : "v"(a), "v"(b)); return r;
}

// Issue all global loads for one t-row chunk into regs R[], ds addrs into DS[].
#define STAGE_LOAD(R, DS, NT, CE_, NIT, T0)                                \
    _Pragma("unroll")                                                      \
    for (int i = 0; i < NIT; ++i) {                                        \
        const int e = lane + i * 64;                                       \
        f2 v = (f2){0.f, 0.f};                                             \
        int da = 0;                                                        \
        if (e < (CE_)) {                                                   \
            const int gq = e / ((NT) * NW), rq = e - gq * ((NT) * NW);     \
            const int tq = rq / NW, wq = rq - tq * NW;                     \
            const int Mq = Mw + gq;                                        \
            da = gq * BUFS + wq * (NT) + tq;                               \
            if (Mq < NM) {                                                 \
                const int nq = Mq >> 4, aq = Mq & 15;                      \
                const int go = (nq * NS + (T0) + tq) * (NA * NW) + aq * NW + wq; \
                v = (f2){x_real[go], x_imag[go]};                          \
            }                                                              \
        }                                                                  \
        R[i] = v; DS[i] = da;                                              \
    }

// Write a register-staged chunk to the wave-private LDS region.
#define STAGE_WRITE(R, DS, CE_, NIT)                                       \
    _Pragma("unroll")                                                      \
    for (int i = 0; i < NIT; ++i) {                                        \
        const int e = lane + i * 64;                                       \
        if (e < (CE_)) wbuf[DS[i]] = R[i];                                 \
    }

// Paired A+B over full rows for NT t's starting at TBASE, chunk layout
// bp[w*NT + t]. w=0 initializes V (F[0][c] = 1/sqrt(33) real -> pk_mul).
#define COMPUTE_CHUNK(NT, TBASE)                                           \
    if (act) {                                                             \
        const f2* bp = wbuf + gg * BUFS;                                   \
        {   /* w = 0: V init */                                            \
            f2 fv[CPT];                                                    \
            _Pragma("unroll")                                              \
            for (int k = 0; k < CPT; ++k) fv[k] = sFsub[c0 + k];           \
            _Pragma("unroll")                                              \
            for (int t = 0; t < (NT); ++t) {                               \
                const f2 xc = bp[t];                                       \
                _Pragma("unroll")                                          \
                for (int k = 0; k < CPT; ++k)                              \
                    V[(TBASE) + t][k] = pkmul_re(xc, fv[k]);               \
            }                                                              \
        }                                                                  \
        _Pragma("unroll 4")                                                \
        for (int wp = 1; wp <= 16; ++wp) {                                 \
            const int wq = NW - wp;                                        \
            f2 xcA[NT], xcB[NT];                                           \
            _Pragma("unroll")                                              \
            for (int t = 0; t < (NT); ++t) xcA[t] = bp[wp * (NT) + t];     \
            _Pragma("unroll")                                              \
            for (int t = 0; t < (NT); ++t) xcB[t] = bp[wq * (NT) + t];     \
            f2 fv[CPT];                                                    \
            _Pragma("unroll")                                              \
            for (int k = 0; k < CPT; ++k) fv[k] = sFsub[wp * NW + c0 + k]; \
            _Pragma("unroll")                                              \
            for (int t = 0; t < (NT); ++t) {                               \
                const f2 u = pkadd(xcA[t], xcB[t]);                        \
                const f2 d = pksub(xcA[t], xcB[t]);                        \
                _Pragma("unroll")                                          \
                for (int k = 0; k < CPT; ++k) {                            \
                    cmac_re(V[(TBASE) + t][k], u, fv[k]);                  \
                    cmac_im(V[(TBASE) + t][k], d, fv[k]);                  \
                }                                                          \
            }                                                              \
        }                                                                  \
    }

__global__ __launch_bounds__(THREADS, 7) void autocorr_kernel(
    const float* __restrict__ x_real, const float* __restrict__ x_imag,
    const float* __restrict__ Fsym_re, const float* __restrict__ Fsym_im,
    const float* __restrict__ Fsub_re, const float* __restrict__ Fsub_im,
    float* __restrict__ out, int NM, int write_complex)
{
    __shared__ f2 sFsym[NS * NS];     // [s][t]
    __shared__ f2 sFsub[SFS];         // rows 0..16 of symmetric Fsub, row-major
    __shared__ f2 buf[GM * BUFS];     // per-matrix 99: x rows chunk, then T2

    const int tid = threadIdx.x;
    const int wave = tid >> 6;
    const int lane = tid & 63;
    const int Mw = blockIdx.x * GM + wave * MPW;
    f2* const wbuf = &buf[wave * MPW * BUFS];

    // ---- F staging (cooperative): only rows 0..16 of Fsub (561 f2) ----
    for (int i = tid; i < SFS; i += THREADS)
        sFsub[i] = (f2){Fsub_re[i], Fsub_im[i]};
    if (tid < NS * NS) sFsym[tid] = (f2){Fsym_re[tid], Fsym_im[tid]};

    // ---- chunk0 (t=0..2): global->reg->LDS, latency overlaps F staging ----
    {
        f2 rr0[IT0]; int ds0[IT0];
        STAGE_LOAD(rr0, ds0, C0T, C0E, IT0, 0);
        STAGE_WRITE(rr0, ds0, C0E, IT0);
    }
    __syncthreads();   // the ONLY barrier

    // ---- chunk1 (t=3,4) loads issue NOW: latency hides under chunk0 compute ----
    f2 rr1[IT1]; int ds1[IT1];
    STAGE_LOAD(rr1, ds1, C1T, C1E, IT1, C0T);

    const int g = lane / TPM;                 // 0..4 active, 5 for idle lanes
    const int j = lane - g * TPM;
    const bool act = (lane < MPW * TPM);      // 55 of 64 lanes compute
    const int gg = act ? g : 0;
    const int M = Mw + gg;
    const int c0 = 3 * j;

    f2 V[NS][CPT];   // initialized inside COMPUTE_CHUNK's w=0 block (act lanes)

    COMPUTE_CHUNK(C0T, 0);

    // ---- chunk1 reg->LDS (overwrites chunk0's region: safe per-wave
    //      in-order DS; compiler inserts the vmcnt for rr1) ----
    STAGE_WRITE(rr1, ds1, C1E, IT1);
    asm volatile("s_waitcnt lgkmcnt(0)" ::: "memory");

    COMPUTE_CHUNK(C1T, C0T);

    // ---- Stage C/D: X = F_sym*V (paired); P = |X|^2; T2 (Hermitian p<3) ----
    f2 T2[3][CPT];
#pragma unroll
    for (int p = 0; p < 3; ++p)
#pragma unroll
        for (int k = 0; k < CPT; ++k) T2[p][k] = (f2){0.f, 0.f};
    if (act) {
        // In-place pairing transform: Fsym[s][4]=conj(Fsym[s][1]),
        // Fsym[s][3]=conj(Fsym[s][2]):  V1<-V1+V4, V4<-V1-V4, V2<-V2+V3, V3<-V2-V3
#pragma unroll
        for (int k = 0; k < CPT; ++k) {
            f2 a = V[1][k], b = V[4][k];
            V[1][k] = pkadd(a, b); V[4][k] = pksub(a, b);
            a = V[2][k]; b = V[3][k];
            V[2][k] = pkadd(a, b); V[3][k] = pksub(a, b);
        }
#pragma unroll
        for (int s = 0; s < NS; ++s) {
            const f2 f0 = sFsym[s * NS + 0];   // = 1/sqrt(5), real
            const f2 f1 = sFsym[s * NS + 1];
            const f2 fc2 = sFsym[s * NS + 2];
            f2 X[CPT];
#pragma unroll
            for (int k = 0; k < CPT; ++k) {
                X[k] = pkmul_re(V[0][k], f0);
                cmac_re(X[k], V[1][k], f1); cmac_im(X[k], V[4][k], f1);
                cmac_re(X[k], V[2][k], fc2); cmac_im(X[k], V[3][k], fc2);
            }
#pragma unroll
            for (int k = 0; k < CPT; ++k) {
                const float Pv = X[k].x * X[k].x + X[k].y * X[k].y;
                const f2 Pp = (f2){Pv, Pv};
#pragma unroll
                for (int p = 0; p < 3; ++p)
                    cmacr(T2[p][k], sFsym[s * NS + p], Pp);
            }
        }
        // T2 col-major into the same wave-private region (after all x reads).
        f2* const wb = wbuf + gg * BUFS;
#pragma unroll
        for (int k = 0; k < CPT; ++k)
#pragma unroll
            for (int p = 0; p < 3; ++p)
                wb[(c0 + k) * 3 + p] = T2[p][k];
    }
    asm volatile("s_waitcnt lgkmcnt(0)" ::: "memory");

    // ---- Stage E: Y[p][q] = sum_v T2[p][v]*conj(Fsub[q][v]), q = c0+k ----
    // Fsub symmetric: F[q][v] = F[v][q] -> read row v, col q (v <= 16 only).
    if (act) {
        const f2* bp = wbuf + gg * BUFS;
        if (!write_complex) {
            // Paired real path: v & 33-v give  su*fr + sd*fi  with
            // su = tcA.x+tcB.x, sd = tcA.y-tcB.y; fold .x+.y at the end.
            f2 Ypk[3][CPT];
            {   // v = 0: F[q][0] = 1/sqrt(33) real -> pk_mul init
                f2 fw[CPT];
#pragma unroll
                for (int k = 0; k < CPT; ++k) fw[k] = sFsub[c0 + k];   // row 0
#pragma unroll
                for (int p = 0; p < 3; ++p) {
                    const f2 tc = bp[p];
#pragma unroll
                    for (int k = 0; k < CPT; ++k)
                        Ypk[p][k] = pkmul(tc, fw[k]);
                }
            }
#pragma unroll 4
            for (int vp = 1; vp <= 16; ++vp) {
                const int vq = NW - vp;
                f2 e2[3];   // built in place: e2 = pkaddsub(A, B)
#pragma unroll
                for (int p = 0; p < 3; ++p) {
                    const f2 ta = bp[vp * 3 + p];
                    const f2 tb = bp[vq * 3 + p];
                    e2[p] = pkaddsub(ta, tb);
                }
                f2 fw[CPT];
#pragma unroll
                for (int k = 0; k < CPT; ++k)
                    fw[k] = sFsub[vp * NW + c0 + k];   // = F[c0+k][vp] by symmetry
#pragma unroll
                for (int p = 0; p < 3; ++p)
#pragma unroll
                    for (int k = 0; k < CPT; ++k)
                        pkfma(Ypk[p][k], e2[p], fw[k]);
            }
            if (M < NM) {
                const int n = M >> 4, a = M & 15;
                const int obase = ((n * NS) * NA + a) * NW;
#pragma unroll
                for (int p = 0; p < 3; ++p) {
                    const int pp = (NS - p) % NS;   // 0,4,3
#pragma unroll
                    for (int k = 0; k < CPT; ++k) {
                        const int q = c0 + k;
                        const int qq = (NW - q) % NW;
                        const float Yr = Ypk[p][k].x + Ypk[p][k].y;
                        out[obase + p * (NA * NW) + q] = Yr;
                        out[obase + pp * (NA * NW) + qq] = Yr;
                    }
                }
            }
        } else {
            // Fallback: full complex output (not expected on this harness).
            f2 Y[3][CPT];
#pragma unroll
            for (int p = 0; p < 3; ++p)
#pragma unroll
                for (int k = 0; k < CPT; ++k) Y[p][k] = (f2){0.f, 0.f};
            for (int v = 0; v < NW; ++v) {
                const int row = (v <= 16) ? v : (NW - v);
                const float sgn = (v <= 16) ? 1.f : -1.f;   // conj for v>16
                f2 tc[3];
#pragma unroll
                for (int p = 0; p < 3; ++p) tc[p] = bp[v * 3 + p];
                f2 fw[CPT];
#pragma unroll
                for (int k = 0; k < CPT; ++k) {
                    f2 f = sFsub[row * NW + c0 + k];
                    f.y *= sgn;
                    fw[k] = f;
                }
#pragma unroll
                for (int p = 0; p < 3; ++p)
#pragma unroll
                    for (int k = 0; k < CPT; ++k) {
                        Y[p][k].x = fmaf(tc[p].x, fw[k].x, Y[p][k].x);
                        Y[p][k].x = fmaf(tc[p].y, fw[k].y, Y[p][k].x);
                        Y[p][k].y = fmaf(tc[p].y, fw[k].x, Y[p][k].y);
                        Y[p][k].y = fmaf(-tc[p].x, fw[k].y, Y[p][k].y);
                    }
            }
            if (M < NM) {
                const int n = M >> 4, a = M & 15;
#pragma unroll
                for (int p = 0; p < 3; ++p) {
                    const int pp = (NS - p) % NS;
#pragma unroll
                    for (int k = 0; k < CPT; ++k) {
                        const int q = c0 + k;
                        const int qq = (NW - q) % NW;
                        ((float2*)out)[((n * NS + p) * NA + a) * NW + q] =
                            make_float2(Y[p][k].x, Y[p][k].y);
                        ((float2*)out)[((n * NS + pp) * NA + a) * NW + qq] =
                            make_float2(Y[p][k].x, -Y[p][k].y);
                    }
                }
            }
        }
    }
}

extern "C" void kernel_launch(void* const* d_in, const int* in_sizes, int n_in,
                              void* d_out, int out_size, void* d_ws, size_t ws_size,
                              hipStream_t stream) {
    const float* x_real  = (const float*)d_in[0];
    const float* x_imag  = (const float*)d_in[1];
    const float* Fsym_re = (const float*)d_in[2];
    const float* Fsym_im = (const float*)d_in[3];
    const float* Fsub_re = (const float*)d_in[4];
    const float* Fsub_im = (const float*)d_in[5];

    const int NM = in_sizes[0] / SW;
    const long long n_cplx = (long long)in_sizes[0];
    const int write_complex = ((long long)out_size >= 2 * n_cplx) ? 1 : 0;

    const int blocks = (NM + GM - 1) / GM;

    autocorr_kernel<<<blocks, THREADS, 0, stream>>>(
        x_real, x_imag, Fsym_re, Fsym_im, Fsub_re, Fsub_im,
        (float*)d_out, NM, write_complex);
}

// Round 10
// 163.799 us; speedup vs baseline: 1.0690x; 1.0690x over previous
//
#include <hip/hip_runtime.h>

#define NS 5      // symbols
#define NW 33     // subcarriers
#define NA 16     // antennas
#define SW 165    // NS*NW
#define BUFS 99   // per-matrix LDS buffer (f2): x rows chunk (<=99), then T2 (99)
#define NFR 17    // Fsub rows stored (0..16; symmetry + conj-mirror covers rest)
#define SFS (NFR*NW)   // 561
#define MPW 5     // matrices per wave
#define GM 20     // matrices per block
#define TPM 11    // threads per matrix
#define CPT 3     // columns per thread
#define THREADS 256

// t-row chunks: chunk0 = t{0,1,2} full rows, chunk1 = t{3,4} full rows.
#define C0T 3
#define C0E (C0T*NW*MPW)   // 495
#define IT0 8
#define C1T 2
#define C1E (C1T*NW*MPW)   // 330
#define IT1 6

// R19: R18's footprint with R17's register budget. launch_bounds' 2nd arg is
// a MINIMUM-waves hint to regalloc, not an occupancy cap: (256,5) gives the
// ~100-VGPR budget this live set needs (R17: 48 VGPR, zero spill; R13/R16/R18
// all spilled under tighter caps), while the 17-row sFsub (R18) keeps LDS at
// 20992 B -> 7 blocks/CU co-resident BY LDS. Expect R17's clean counters
// (WRITE 42.5 MB, FETCH ~45 MB) at R18's occupancy (~56%).
typedef float f2 __attribute__((ext_vector_type(2)));

// z += u * Re(f):  (z.x += u.x*f.lo, z.y += u.y*f.lo)
__device__ __forceinline__ void cmac_re(f2& z, f2 u, f2 f) {
    asm("v_pk_fma_f32 %0, %1, %2, %0 op_sel:[0,0,0] op_sel_hi:[1,0,1]"
        : "+v"(z) : "v"(u), "v"(f));
}
// z += i * d * Im(f):  (z.x += -d.y*f.hi, z.y += d.x*f.hi)
__device__ __forceinline__ void cmac_im(f2& z, f2 d, f2 f) {
    asm("v_pk_fma_f32 %0, %1, %2, %0 op_sel:[1,1,0] op_sel_hi:[0,1,1] neg_lo:[1,0,0]"
        : "+v"(z) : "v"(d), "v"(f));
}
// z += conj(f) * P, P real pair Pp=(P,P): lo zr+=f.x*P, hi zi+=-f.y*P
__device__ __forceinline__ void cmacr(f2& z, f2 f, f2 Pp) {
    asm("v_pk_fma_f32 %0, %1, %2, %0 op_sel:[0,0,0] op_sel_hi:[1,1,1] neg_hi:[1,0,0]"
        : "+v"(z) : "v"(f), "v"(Pp));
}
// plain packed: z += a*b elementwise
__device__ __forceinline__ void pkfma(f2& z, f2 a, f2 b) {
    asm("v_pk_fma_f32 %0, %1, %2, %0 op_sel:[0,0,0] op_sel_hi:[1,1,1]"
        : "+v"(z) : "v"(a), "v"(b));
}
// r = a + b (packed)
__device__ __forceinline__ f2 pkadd(f2 a, f2 b) {
    f2 r; asm("v_pk_add_f32 %0, %1, %2" : "=v"(r) : "v"(a), "v"(b)); return r;
}
// r = a - b (packed)
__device__ __forceinline__ f2 pksub(f2 a, f2 b) {
    f2 r; asm("v_pk_add_f32 %0, %1, %2 neg_lo:[0,1] neg_hi:[0,1]"
              : "=v"(r) : "v"(a), "v"(b)); return r;
}
// r = (a.x + b.x, a.y - b.y)
__device__ __forceinline__ f2 pkaddsub(f2 a, f2 b) {
    f2 r; asm("v_pk_add_f32 %0, %1, %2 neg_hi:[0,1]"
              : "=v"(r) : "v"(a), "v"(b)); return r;
}
// r = u * Re(f) broadcast: (u.x*f.lo, u.y*f.lo)  -- accumulator init
__device__ __forceinline__ f2 pkmul_re(f2 u, f2 f) {
    f2 r; asm("v_pk_mul_f32 %0, %1, %2 op_sel:[0,0] op_sel_hi:[1,0]"
              : "=v"(r) : "v"(u), "v"(f)); return r;
}
// r = a * b elementwise -- accumulator init
__device__ __forceinline__ f2 pkmul(f2 a, f2 b) {
    f2 r; asm("v_pk_mul_f32 %0, %1, %2" : "=v"(r) : "v"(a), "v"(b)); return r;
}

// Issue all global loads for one t-row chunk into regs R[], ds addrs into DS[].
#define STAGE_LOAD(R, DS, NT, CE_, NIT, T0)                                \
    _Pragma("unroll")                                                      \
    for (int i = 0; i < NIT; ++i) {                                        \
        const int e = lane + i * 64;                                       \
        f2 v = (f2){0.f, 0.f};                                             \
        int da = 0;                                                        \
        if (e < (CE_)) {                                                   \
            const int gq = e / ((NT) * NW), rq = e - gq * ((NT) * NW);     \
            const int tq = rq / NW, wq = rq - tq * NW;                     \
            const int Mq = Mw + gq;                                        \
            da = gq * BUFS + wq * (NT) + tq;                               \
            if (Mq < NM) {                                                 \
                const int nq = Mq >> 4, aq = Mq & 15;                      \
                const int go = (nq * NS + (T0) + tq) * (NA * NW) + aq * NW + wq; \
                v = (f2){x_real[go], x_imag[go]};                          \
            }                                                              \
        }                                                                  \
        R[i] = v; DS[i] = da;                                              \
    }

// Write a register-staged chunk to the wave-private LDS region.
#define STAGE_WRITE(R, DS, CE_, NIT)                                       \
    _Pragma("unroll")                                                      \
    for (int i = 0; i < NIT; ++i) {                                        \
        const int e = lane + i * 64;                                       \
        if (e < (CE_)) wbuf[DS[i]] = R[i];                                 \
    }

// Paired A+B over full rows for NT t's starting at TBASE, chunk layout
// bp[w*NT + t]. w=0 initializes V (F[0][c] = 1/sqrt(33) real -> pk_mul).
#define COMPUTE_CHUNK(NT, TBASE)                                           \
    if (act) {                                                             \
        const f2* bp = wbuf + gg * BUFS;                                   \
        {   /* w = 0: V init */                                            \
            f2 fv[CPT];                                                    \
            _Pragma("unroll")                                              \
            for (int k = 0; k < CPT; ++k) fv[k] = sFsub[c0 + k];           \
            _Pragma("unroll")                                              \
            for (int t = 0; t < (NT); ++t) {                               \
                const f2 xc = bp[t];                                       \
                _Pragma("unroll")                                          \
                for (int k = 0; k < CPT; ++k)                              \
                    V[(TBASE) + t][k] = pkmul_re(xc, fv[k]);               \
            }                                                              \
        }                                                                  \
        _Pragma("unroll 4")                                                \
        for (int wp = 1; wp <= 16; ++wp) {                                 \
            const int wq = NW - wp;                                        \
            f2 xcA[NT], xcB[NT];                                           \
            _Pragma("unroll")                                              \
            for (int t = 0; t < (NT); ++t) xcA[t] = bp[wp * (NT) + t];     \
            _Pragma("unroll")                                              \
            for (int t = 0; t < (NT); ++t) xcB[t] = bp[wq * (NT) + t];     \
            f2 fv[CPT];                                                    \
            _Pragma("unroll")                                              \
            for (int k = 0; k < CPT; ++k) fv[k] = sFsub[wp * NW + c0 + k]; \
            _Pragma("unroll")                                              \
            for (int t = 0; t < (NT); ++t) {                               \
                const f2 u = pkadd(xcA[t], xcB[t]);                        \
                const f2 d = pksub(xcA[t], xcB[t]);                        \
                _Pragma("unroll")                                          \
                for (int k = 0; k < CPT; ++k) {                            \
                    cmac_re(V[(TBASE) + t][k], u, fv[k]);                  \
                    cmac_im(V[(TBASE) + t][k], d, fv[k]);                  \
                }                                                          \
            }                                                              \
        }                                                                  \
    }

__global__ __launch_bounds__(THREADS, 5) void autocorr_kernel(
    const float* __restrict__ x_real, const float* __restrict__ x_imag,
    const float* __restrict__ Fsym_re, const float* __restrict__ Fsym_im,
    const float* __restrict__ Fsub_re, const float* __restrict__ Fsub_im,
    float* __restrict__ out, int NM, int write_complex)
{
    __shared__ f2 sFsym[NS * NS];     // [s][t]
    __shared__ f2 sFsub[SFS];         // rows 0..16 of symmetric Fsub, row-major
    __shared__ f2 buf[GM * BUFS];     // per-matrix 99: x rows chunk, then T2

    const int tid = threadIdx.x;
    const int wave = tid >> 6;
    const int lane = tid & 63;
    const int Mw = blockIdx.x * GM + wave * MPW;
    f2* const wbuf = &buf[wave * MPW * BUFS];

    // ---- F staging (cooperative): only rows 0..16 of Fsub (561 f2) ----
    for (int i = tid; i < SFS; i += THREADS)
        sFsub[i] = (f2){Fsub_re[i], Fsub_im[i]};
    if (tid < NS * NS) sFsym[tid] = (f2){Fsym_re[tid], Fsym_im[tid]};

    // ---- chunk0 (t=0..2): global->reg->LDS, latency overlaps F staging ----
    {
        f2 rr0[IT0]; int ds0[IT0];
        STAGE_LOAD(rr0, ds0, C0T, C0E, IT0, 0);
        STAGE_WRITE(rr0, ds0, C0E, IT0);
    }
    __syncthreads();   // the ONLY barrier

    // ---- chunk1 (t=3,4) loads issue NOW: latency hides under chunk0 compute ----
    f2 rr1[IT1]; int ds1[IT1];
    STAGE_LOAD(rr1, ds1, C1T, C1E, IT1, C0T);

    const int g = lane / TPM;                 // 0..4 active, 5 for idle lanes
    const int j = lane - g * TPM;
    const bool act = (lane < MPW * TPM);      // 55 of 64 lanes compute
    const int gg = act ? g : 0;
    const int M = Mw + gg;
    const int c0 = 3 * j;

    f2 V[NS][CPT];   // initialized inside COMPUTE_CHUNK's w=0 block (act lanes)

    COMPUTE_CHUNK(C0T, 0);

    // ---- chunk1 reg->LDS (overwrites chunk0's region: safe per-wave
    //      in-order DS; compiler inserts the vmcnt for rr1) ----
    STAGE_WRITE(rr1, ds1, C1E, IT1);
    asm volatile("s_waitcnt lgkmcnt(0)" ::: "memory");

    COMPUTE_CHUNK(C1T, C0T);

    // ---- Stage C/D: X = F_sym*V (paired); P = |X|^2; T2 (Hermitian p<3) ----
    f2 T2[3][CPT];
#pragma unroll
    for (int p = 0; p < 3; ++p)
#pragma unroll
        for (int k = 0; k < CPT; ++k) T2[p][k] = (f2){0.f, 0.f};
    if (act) {
        // In-place pairing transform: Fsym[s][4]=conj(Fsym[s][1]),
        // Fsym[s][3]=conj(Fsym[s][2]):  V1<-V1+V4, V4<-V1-V4, V2<-V2+V3, V3<-V2-V3
#pragma unroll
        for (int k = 0; k < CPT; ++k) {
            f2 a = V[1][k], b = V[4][k];
            V[1][k] = pkadd(a, b); V[4][k] = pksub(a, b);
            a = V[2][k]; b = V[3][k];
            V[2][k] = pkadd(a, b); V[3][k] = pksub(a, b);
        }
#pragma unroll
        for (int s = 0; s < NS; ++s) {
            const f2 f0 = sFsym[s * NS + 0];   // = 1/sqrt(5), real
            const f2 f1 = sFsym[s * NS + 1];
            const f2 fc2 = sFsym[s * NS + 2];
            f2 X[CPT];
#pragma unroll
            for (int k = 0; k < CPT; ++k) {
                X[k] = pkmul_re(V[0][k], f0);
                cmac_re(X[k], V[1][k], f1); cmac_im(X[k], V[4][k], f1);
                cmac_re(X[k], V[2][k], fc2); cmac_im(X[k], V[3][k], fc2);
            }
#pragma unroll
            for (int k = 0; k < CPT; ++k) {
                const float Pv = X[k].x * X[k].x + X[k].y * X[k].y;
                const f2 Pp = (f2){Pv, Pv};
#pragma unroll
                for (int p = 0; p < 3; ++p)
                    cmacr(T2[p][k], sFsym[s * NS + p], Pp);
            }
        }
        // T2 col-major into the same wave-private region (after all x reads).
        f2* const wb = wbuf + gg * BUFS;
#pragma unroll
        for (int k = 0; k < CPT; ++k)
#pragma unroll
            for (int p = 0; p < 3; ++p)
                wb[(c0 + k) * 3 + p] = T2[p][k];
    }
    asm volatile("s_waitcnt lgkmcnt(0)" ::: "memory");

    // ---- Stage E: Y[p][q] = sum_v T2[p][v]*conj(Fsub[q][v]), q = c0+k ----
    // Fsub symmetric: F[q][v] = F[v][q] -> read row v, col q (v <= 16 only).
    if (act) {
        const f2* bp = wbuf + gg * BUFS;
        if (!write_complex) {
            // Paired real path: v & 33-v give  su*fr + sd*fi  with
            // su = tcA.x+tcB.x, sd = tcA.y-tcB.y; fold .x+.y at the end.
            f2 Ypk[3][CPT];
            {   // v = 0: F[q][0] = 1/sqrt(33) real -> pk_mul init
                f2 fw[CPT];
#pragma unroll
                for (int k = 0; k < CPT; ++k) fw[k] = sFsub[c0 + k];   // row 0
#pragma unroll
                for (int p = 0; p < 3; ++p) {
                    const f2 tc = bp[p];
#pragma unroll
                    for (int k = 0; k < CPT; ++k)
                        Ypk[p][k] = pkmul(tc, fw[k]);
                }
            }
#pragma unroll 4
            for (int vp = 1; vp <= 16; ++vp) {
                const int vq = NW - vp;
                f2 e2[3];   // built in place: e2 = pkaddsub(A, B)
#pragma unroll
                for (int p = 0; p < 3; ++p) {
                    const f2 ta = bp[vp * 3 + p];
                    const f2 tb = bp[vq * 3 + p];
                    e2[p] = pkaddsub(ta, tb);
                }
                f2 fw[CPT];
#pragma unroll
                for (int k = 0; k < CPT; ++k)
                    fw[k] = sFsub[vp * NW + c0 + k];   // = F[c0+k][vp] by symmetry
#pragma unroll
                for (int p = 0; p < 3; ++p)
#pragma unroll
                    for (int k = 0; k < CPT; ++k)
                        pkfma(Ypk[p][k], e2[p], fw[k]);
            }
            if (M < NM) {
                const int n = M >> 4, a = M & 15;
                const int obase = ((n * NS) * NA + a) * NW;
#pragma unroll
                for (int p = 0; p < 3; ++p) {
                    const int pp = (NS - p) % NS;   // 0,4,3
#pragma unroll
                    for (int k = 0; k < CPT; ++k) {
                        const int q = c0 + k;
                        const int qq = (NW - q) % NW;
                        const float Yr = Ypk[p][k].x + Ypk[p][k].y;
                        out[obase + p * (NA * NW) + q] = Yr;
                        out[obase + pp * (NA * NW) + qq] = Yr;
                    }
                }
            }
        } else {
            // Fallback: full complex output (not expected on this harness).
            f2 Y[3][CPT];
#pragma unroll
            for (int p = 0; p < 3; ++p)
#pragma unroll
                for (int k = 0; k < CPT; ++k) Y[p][k] = (f2){0.f, 0.f};
            for (int v = 0; v < NW; ++v) {
                const int row = (v <= 16) ? v : (NW - v);
                const float sgn = (v <= 16) ? 1.f : -1.f;   // conj for v>16
                f2 tc[3];
#pragma unroll
                for (int p = 0; p < 3; ++p) tc[p] = bp[v * 3 + p];
                f2 fw[CPT];
#pragma unroll
                for (int k = 0; k < CPT; ++k) {
                    f2 f = sFsub[row * NW + c0 + k];
                    f.y *= sgn;
                    fw[k] = f;
                }
#pragma unroll
                for (int p = 0; p < 3; ++p)
#pragma unroll
                    for (int k = 0; k < CPT; ++k) {
                        Y[p][k].x = fmaf(tc[p].x, fw[k].x, Y[p][k].x);
                        Y[p][k].x = fmaf(tc[p].y, fw[k].y, Y[p][k].x);
                        Y[p][k].y = fmaf(tc[p].y, fw[k].x, Y[p][k].y);
                        Y[p][k].y = fmaf(-tc[p].x, fw[k].y, Y[p][k].y);
                    }
            }
            if (M < NM) {
                const int n = M >> 4, a = M & 15;
#pragma unroll
                for (int p = 0; p < 3; ++p) {
                    const int pp = (NS - p) % NS;
#pragma unroll
                    for (int k = 0; k < CPT; ++k) {
                        const int q = c0 + k;
                        const int qq = (NW - q) % NW;
                        ((float2*)out)[((n * NS + p) * NA + a) * NW + q] =
                            make_float2(Y[p][k].x, Y[p][k].y);
                        ((float2*)out)[((n * NS + pp) * NA + a) * NW + qq] =
                            make_float2(Y[p][k].x, -Y[p][k].y);
                    }
                }
            }
        }
    }
}

extern "C" void kernel_launch(void* const* d_in, const int* in_sizes, int n_in,
                              void* d_out, int out_size, void* d_ws, size_t ws_size,
                              hipStream_t stream) {
    const float* x_real  = (const float*)d_in[0];
    const float* x_imag  = (const float*)d_in[1];
    const float* Fsym_re = (const float*)d_in[2];
    const float* Fsym_im = (const float*)d_in[3];
    const float* Fsub_re = (const float*)d_in[4];
    const float* Fsub_im = (const float*)d_in[5];

    const int NM = in_sizes[0] / SW;
    const long long n_cplx = (long long)in_sizes[0];
    const int write_complex = ((long long)out_size >= 2 * n_cplx) ? 1 : 0;

    const int blocks = (NM + GM - 1) / GM;

    autocorr_kernel<<<blocks, THREADS, 0, stream>>>(
        x_real, x_imag, Fsym_re, Fsym_im, Fsub_re, Fsub_im,
        (float*)d_out, NM, write_complex);
}

// Round 11
// 159.115 us; speedup vs baseline: 1.1005x; 1.0294x over previous
//
#include <hip/hip_runtime.h>

#define NS 5      // symbols
#define NW 33     // subcarriers
#define NA 16     // antennas
#define SW 165    // NS*NW
#define BUFS 99   // per-matrix LDS buffer (f2): x rows chunk (<=99), then T2 (99)
#define NFR 17    // Fsub rows stored (0..16; symmetry + conj-mirror covers rest)
#define SFS (NFR*NW)   // 561
#define MPW 5     // matrices per wave
#define GM 20     // matrices per block
#define TPM 11    // threads per matrix
#define CPT 3     // columns per thread
#define THREADS 256

// t-row chunks: chunk0 = t{0,1,2} full rows, chunk1 = t{3,4} full rows.
#define C0T 3
#define C0E (C0T*NW*MPW)   // 495
#define IT0 8
#define C1T 2
#define C1E (C1T*NW*MPW)   // 330
#define IT1 6

// R20: occupancy dial up one notch without spill. Measured law (R11..R19):
// hipcc's launch_bounds 2nd arg sets BOTH the residency target (occ ~= 8.3%*N)
// and the VGPR squeeze (~68-4.6N); spill whenever natural pressure exceeds
// that. R19 = arg5/48VGPR/41%occ clean. Here: arg6 (budget ~40) paired with
// making chunk1 staging transient again (drops the rr1/ds1 prefetch held
// across chunk0 compute, ~18 nominal regs) so pressure fits. T14 regime:
// prefetch value shrinks as TLP rises. Tripwire = WRITE_SIZE (spill shows as
// +MBs there). Kept: 17-row sFsub (R18), conj-pair math (R16), pk_fma (R11),
// wave-autonomy (R10), LDS-coalesced staging (R12 lesson).
typedef float f2 __attribute__((ext_vector_type(2)));

// z += u * Re(f):  (z.x += u.x*f.lo, z.y += u.y*f.lo)
__device__ __forceinline__ void cmac_re(f2& z, f2 u, f2 f) {
    asm("v_pk_fma_f32 %0, %1, %2, %0 op_sel:[0,0,0] op_sel_hi:[1,0,1]"
        : "+v"(z) : "v"(u), "v"(f));
}
// z += i * d * Im(f):  (z.x += -d.y*f.hi, z.y += d.x*f.hi)
__device__ __forceinline__ void cmac_im(f2& z, f2 d, f2 f) {
    asm("v_pk_fma_f32 %0, %1, %2, %0 op_sel:[1,1,0] op_sel_hi:[0,1,1] neg_lo:[1,0,0]"
        : "+v"(z) : "v"(d), "v"(f));
}
// z += conj(f) * P, P real pair Pp=(P,P): lo zr+=f.x*P, hi zi+=-f.y*P
__device__ __forceinline__ void cmacr(f2& z, f2 f, f2 Pp) {
    asm("v_pk_fma_f32 %0, %1, %2, %0 op_sel:[0,0,0] op_sel_hi:[1,1,1] neg_hi:[1,0,0]"
        : "+v"(z) : "v"(f), "v"(Pp));
}
// plain packed: z += a*b elementwise
__device__ __forceinline__ void pkfma(f2& z, f2 a, f2 b) {
    asm("v_pk_fma_f32 %0, %1, %2, %0 op_sel:[0,0,0] op_sel_hi:[1,1,1]"
        : "+v"(z) : "v"(a), "v"(b));
}
// r = a + b (packed)
__device__ __forceinline__ f2 pkadd(f2 a, f2 b) {
    f2 r; asm("v_pk_add_f32 %0, %1, %2" : "=v"(r) : "v"(a), "v"(b)); return r;
}
// r = a - b (packed)
__device__ __forceinline__ f2 pksub(f2 a, f2 b) {
    f2 r; asm("v_pk_add_f32 %0, %1, %2 neg_lo:[0,1] neg_hi:[0,1]"
              : "=v"(r) : "v"(a), "v"(b)); return r;
}
// r = (a.x + b.x, a.y - b.y)
__device__ __forceinline__ f2 pkaddsub(f2 a, f2 b) {
    f2 r; asm("v_pk_add_f32 %0, %1, %2 neg_hi:[0,1]"
              : "=v"(r) : "v"(a), "v"(b)); return r;
}
// r = u * Re(f) broadcast: (u.x*f.lo, u.y*f.lo)  -- accumulator init
__device__ __forceinline__ f2 pkmul_re(f2 u, f2 f) {
    f2 r; asm("v_pk_mul_f32 %0, %1, %2 op_sel:[0,0] op_sel_hi:[1,0]"
              : "=v"(r) : "v"(u), "v"(f)); return r;
}
// r = a * b elementwise -- accumulator init
__device__ __forceinline__ f2 pkmul(f2 a, f2 b) {
    f2 r; asm("v_pk_mul_f32 %0, %1, %2" : "=v"(r) : "v"(a), "v"(b)); return r;
}

// Issue all global loads for one t-row chunk into regs R[], ds addrs into DS[].
#define STAGE_LOAD(R, DS, NT, CE_, NIT, T0)                                \
    _Pragma("unroll")                                                      \
    for (int i = 0; i < NIT; ++i) {                                        \
        const int e = lane + i * 64;                                       \
        f2 v = (f2){0.f, 0.f};                                             \
        int da = 0;                                                        \
        if (e < (CE_)) {                                                   \
            const int gq = e / ((NT) * NW), rq = e - gq * ((NT) * NW);     \
            const int tq = rq / NW, wq = rq - tq * NW;                     \
            const int Mq = Mw + gq;                                        \
            da = gq * BUFS + wq * (NT) + tq;                               \
            if (Mq < NM) {                                                 \
                const int nq = Mq >> 4, aq = Mq & 15;                      \
                const int go = (nq * NS + (T0) + tq) * (NA * NW) + aq * NW + wq; \
                v = (f2){x_real[go], x_imag[go]};                          \
            }                                                              \
        }                                                                  \
        R[i] = v; DS[i] = da;                                              \
    }

// Write a register-staged chunk to the wave-private LDS region.
#define STAGE_WRITE(R, DS, CE_, NIT)                                       \
    _Pragma("unroll")                                                      \
    for (int i = 0; i < NIT; ++i) {                                        \
        const int e = lane + i * 64;                                       \
        if (e < (CE_)) wbuf[DS[i]] = R[i];                                 \
    }

// Paired A+B over full rows for NT t's starting at TBASE, chunk layout
// bp[w*NT + t]. w=0 initializes V (F[0][c] = 1/sqrt(33) real -> pk_mul).
#define COMPUTE_CHUNK(NT, TBASE)                                           \
    if (act) {                                                             \
        const f2* bp = wbuf + gg * BUFS;                                   \
        {   /* w = 0: V init */                                            \
            f2 fv[CPT];                                                    \
            _Pragma("unroll")                                              \
            for (int k = 0; k < CPT; ++k) fv[k] = sFsub[c0 + k];           \
            _Pragma("unroll")                                              \
            for (int t = 0; t < (NT); ++t) {                               \
                const f2 xc = bp[t];                                       \
                _Pragma("unroll")                                          \
                for (int k = 0; k < CPT; ++k)                              \
                    V[(TBASE) + t][k] = pkmul_re(xc, fv[k]);               \
            }                                                              \
        }                                                                  \
        _Pragma("unroll 4")                                                \
        for (int wp = 1; wp <= 16; ++wp) {                                 \
            const int wq = NW - wp;                                        \
            f2 xcA[NT], xcB[NT];                                           \
            _Pragma("unroll")                                              \
            for (int t = 0; t < (NT); ++t) xcA[t] = bp[wp * (NT) + t];     \
            _Pragma("unroll")                                              \
            for (int t = 0; t < (NT); ++t) xcB[t] = bp[wq * (NT) + t];     \
            f2 fv[CPT];                                                    \
            _Pragma("unroll")                                              \
            for (int k = 0; k < CPT; ++k) fv[k] = sFsub[wp * NW + c0 + k]; \
            _Pragma("unroll")                                              \
            for (int t = 0; t < (NT); ++t) {                               \
                const f2 u = pkadd(xcA[t], xcB[t]);                        \
                const f2 d = pksub(xcA[t], xcB[t]);                        \
                _Pragma("unroll")                                          \
                for (int k = 0; k < CPT; ++k) {                            \
                    cmac_re(V[(TBASE) + t][k], u, fv[k]);                  \
                    cmac_im(V[(TBASE) + t][k], d, fv[k]);                  \
                }                                                          \
            }                                                              \
        }                                                                  \
    }

__global__ __launch_bounds__(THREADS, 6) void autocorr_kernel(
    const float* __restrict__ x_real, const float* __restrict__ x_imag,
    const float* __restrict__ Fsym_re, const float* __restrict__ Fsym_im,
    const float* __restrict__ Fsub_re, const float* __restrict__ Fsub_im,
    float* __restrict__ out, int NM, int write_complex)
{
    __shared__ f2 sFsym[NS * NS];     // [s][t]
    __shared__ f2 sFsub[SFS];         // rows 0..16 of symmetric Fsub, row-major
    __shared__ f2 buf[GM * BUFS];     // per-matrix 99: x rows chunk, then T2

    const int tid = threadIdx.x;
    const int wave = tid >> 6;
    const int lane = tid & 63;
    const int Mw = blockIdx.x * GM + wave * MPW;
    f2* const wbuf = &buf[wave * MPW * BUFS];

    // ---- F staging (cooperative): only rows 0..16 of Fsub (561 f2) ----
    for (int i = tid; i < SFS; i += THREADS)
        sFsub[i] = (f2){Fsub_re[i], Fsub_im[i]};
    if (tid < NS * NS) sFsym[tid] = (f2){Fsym_re[tid], Fsym_im[tid]};

    // ---- chunk0 (t=0..2): global->reg->LDS, latency overlaps F staging ----
    {
        f2 rr0[IT0]; int ds0[IT0];
        STAGE_LOAD(rr0, ds0, C0T, C0E, IT0, 0);
        STAGE_WRITE(rr0, ds0, C0E, IT0);
    }
    __syncthreads();   // the ONLY barrier

    const int g = lane / TPM;                 // 0..4 active, 5 for idle lanes
    const int j = lane - g * TPM;
    const bool act = (lane < MPW * TPM);      // 55 of 64 lanes compute
    const int gg = act ? g : 0;
    const int M = Mw + gg;
    const int c0 = 3 * j;

    f2 V[NS][CPT];   // initialized inside COMPUTE_CHUNK's w=0 block (act lanes)

    COMPUTE_CHUNK(C0T, 0);

    // ---- chunk1 (t=3,4): transient staging (regs dead immediately; no
    //      pressure across compute -- the arg6 budget is ~40 VGPR). TLP at
    //      ~5 waves/SIMD covers the exposed load latency (T14 regime).
    //      Overwrites chunk0's region: safe per-wave in-order DS. ----
    {
        f2 rr1[IT1]; int ds1[IT1];
        STAGE_LOAD(rr1, ds1, C1T, C1E, IT1, C0T);
        STAGE_WRITE(rr1, ds1, C1E, IT1);
    }
    asm volatile("s_waitcnt lgkmcnt(0)" ::: "memory");

    COMPUTE_CHUNK(C1T, C0T);

    // ---- Stage C/D: X = F_sym*V (paired); P = |X|^2; T2 (Hermitian p<3) ----
    f2 T2[3][CPT];
#pragma unroll
    for (int p = 0; p < 3; ++p)
#pragma unroll
        for (int k = 0; k < CPT; ++k) T2[p][k] = (f2){0.f, 0.f};
    if (act) {
        // In-place pairing transform: Fsym[s][4]=conj(Fsym[s][1]),
        // Fsym[s][3]=conj(Fsym[s][2]):  V1<-V1+V4, V4<-V1-V4, V2<-V2+V3, V3<-V2-V3
#pragma unroll
        for (int k = 0; k < CPT; ++k) {
            f2 a = V[1][k], b = V[4][k];
            V[1][k] = pkadd(a, b); V[4][k] = pksub(a, b);
            a = V[2][k]; b = V[3][k];
            V[2][k] = pkadd(a, b); V[3][k] = pksub(a, b);
        }
#pragma unroll
        for (int s = 0; s < NS; ++s) {
            const f2 f0 = sFsym[s * NS + 0];   // = 1/sqrt(5), real
            const f2 f1 = sFsym[s * NS + 1];
            const f2 fc2 = sFsym[s * NS + 2];
            f2 X[CPT];
#pragma unroll
            for (int k = 0; k < CPT; ++k) {
                X[k] = pkmul_re(V[0][k], f0);
                cmac_re(X[k], V[1][k], f1); cmac_im(X[k], V[4][k], f1);
                cmac_re(X[k], V[2][k], fc2); cmac_im(X[k], V[3][k], fc2);
            }
#pragma unroll
            for (int k = 0; k < CPT; ++k) {
                const float Pv = X[k].x * X[k].x + X[k].y * X[k].y;
                const f2 Pp = (f2){Pv, Pv};
#pragma unroll
                for (int p = 0; p < 3; ++p)
                    cmacr(T2[p][k], sFsym[s * NS + p], Pp);
            }
        }
        // T2 col-major into the same wave-private region (after all x reads).
        f2* const wb = wbuf + gg * BUFS;
#pragma unroll
        for (int k = 0; k < CPT; ++k)
#pragma unroll
            for (int p = 0; p < 3; ++p)
                wb[(c0 + k) * 3 + p] = T2[p][k];
    }
    asm volatile("s_waitcnt lgkmcnt(0)" ::: "memory");

    // ---- Stage E: Y[p][q] = sum_v T2[p][v]*conj(Fsub[q][v]), q = c0+k ----
    // Fsub symmetric: F[q][v] = F[v][q] -> read row v, col q (v <= 16 only).
    if (act) {
        const f2* bp = wbuf + gg * BUFS;
        if (!write_complex) {
            // Paired real path: v & 33-v give  su*fr + sd*fi  with
            // su = tcA.x+tcB.x, sd = tcA.y-tcB.y; fold .x+.y at the end.
            f2 Ypk[3][CPT];
            {   // v = 0: F[q][0] = 1/sqrt(33) real -> pk_mul init
                f2 fw[CPT];
#pragma unroll
                for (int k = 0; k < CPT; ++k) fw[k] = sFsub[c0 + k];   // row 0
#pragma unroll
                for (int p = 0; p < 3; ++p) {
                    const f2 tc = bp[p];
#pragma unroll
                    for (int k = 0; k < CPT; ++k)
                        Ypk[p][k] = pkmul(tc, fw[k]);
                }
            }
#pragma unroll 4
            for (int vp = 1; vp <= 16; ++vp) {
                const int vq = NW - vp;
                f2 e2[3];   // built in place: e2 = pkaddsub(A, B)
#pragma unroll
                for (int p = 0; p < 3; ++p) {
                    const f2 ta = bp[vp * 3 + p];
                    const f2 tb = bp[vq * 3 + p];
                    e2[p] = pkaddsub(ta, tb);
                }
                f2 fw[CPT];
#pragma unroll
                for (int k = 0; k < CPT; ++k)
                    fw[k] = sFsub[vp * NW + c0 + k];   // = F[c0+k][vp] by symmetry
#pragma unroll
                for (int p = 0; p < 3; ++p)
#pragma unroll
                    for (int k = 0; k < CPT; ++k)
                        pkfma(Ypk[p][k], e2[p], fw[k]);
            }
            if (M < NM) {
                const int n = M >> 4, a = M & 15;
                const int obase = ((n * NS) * NA + a) * NW;
#pragma unroll
                for (int p = 0; p < 3; ++p) {
                    const int pp = (NS - p) % NS;   // 0,4,3
#pragma unroll
                    for (int k = 0; k < CPT; ++k) {
                        const int q = c0 + k;
                        const int qq = (NW - q) % NW;
                        const float Yr = Ypk[p][k].x + Ypk[p][k].y;
                        out[obase + p * (NA * NW) + q] = Yr;
                        out[obase + pp * (NA * NW) + qq] = Yr;
                    }
                }
            }
        } else {
            // Fallback: full complex output (not expected on this harness).
            f2 Y[3][CPT];
#pragma unroll
            for (int p = 0; p < 3; ++p)
#pragma unroll
                for (int k = 0; k < CPT; ++k) Y[p][k] = (f2){0.f, 0.f};
            for (int v = 0; v < NW; ++v) {
                const int row = (v <= 16) ? v : (NW - v);
                const float sgn = (v <= 16) ? 1.f : -1.f;   // conj for v>16
                f2 tc[3];
#pragma unroll
                for (int p = 0; p < 3; ++p) tc[p] = bp[v * 3 + p];
                f2 fw[CPT];
#pragma unroll
                for (int k = 0; k < CPT; ++k) {
                    f2 f = sFsub[row * NW + c0 + k];
                    f.y *= sgn;
                    fw[k] = f;
                }
#pragma unroll
                for (int p = 0; p < 3; ++p)
#pragma unroll
                    for (int k = 0; k < CPT; ++k) {
                        Y[p][k].x = fmaf(tc[p].x, fw[k].x, Y[p][k].x);
                        Y[p][k].x = fmaf(tc[p].y, fw[k].y, Y[p][k].x);
                        Y[p][k].y = fmaf(tc[p].y, fw[k].x, Y[p][k].y);
                        Y[p][k].y = fmaf(-tc[p].x, fw[k].y, Y[p][k].y);
                    }
            }
            if (M < NM) {
                const int n = M >> 4, a = M & 15;
#pragma unroll
                for (int p = 0; p < 3; ++p) {
                    const int pp = (NS - p) % NS;
#pragma unroll
                    for (int k = 0; k < CPT; ++k) {
                        const int q = c0 + k;
                        const int qq = (NW - q) % NW;
                        ((float2*)out)[((n * NS + p) * NA + a) * NW + q] =
                            make_float2(Y[p][k].x, Y[p][k].y);
                        ((float2*)out)[((n * NS + pp) * NA + a) * NW + qq] =
                            make_float2(Y[p][k].x, -Y[p][k].y);
                    }
                }
            }
        }
    }
}

extern "C" void kernel_launch(void* const* d_in, const int* in_sizes, int n_in,
                              void* d_out, int out_size, void* d_ws, size_t ws_size,
                              hipStream_t stream) {
    const float* x_real  = (const float*)d_in[0];
    const float* x_imag  = (const float*)d_in[1];
    const float* Fsym_re = (const float*)d_in[2];
    const float* Fsym_im = (const float*)d_in[3];
    const float* Fsub_re = (const float*)d_in[4];
    const float* Fsub_im = (const float*)d_in[5];

    const int NM = in_sizes[0] / SW;
    const long long n_cplx = (long long)in_sizes[0];
    const int write_complex = ((long long)out_size >= 2 * n_cplx) ? 1 : 0;

    const int blocks = (NM + GM - 1) / GM;

    autocorr_kernel<<<blocks, THREADS, 0, stream>>>(
        x_real, x_imag, Fsym_re, Fsym_im, Fsub_re, Fsub_im,
        (float*)d_out, NM, write_complex);
}